// Round 1
// baseline (2729.032 us; speedup 1.0000x reference)
//
#include <hip/hip_runtime.h>

// Problem dims (fixed by reference setup_inputs)
constexpr int Bsz = 32768;
constexpr int Ksz = 4096;
constexpr int Dsz = 256;

// Tiling for the fused distance-GEMM + argmin
constexpr int BM = 128;          // rows per block
constexpr int BN = 128;          // codes per k-chunk
constexpr int DC = 32;           // D-chunk staged in LDS
constexpr int SPLITK = 4;        // K split across blocks for occupancy
constexpr int KC_PER_SPLIT = Ksz / BN / SPLITK;  // 8
constexpr int LDSS = 36;         // LDS row stride (floats), pad 32->36 for bank spread

// ---------------------------------------------------------------------------
// Kernel 0: per-code squared norms ||e_k||^2  -> ws
// ---------------------------------------------------------------------------
__global__ __launch_bounds__(256) void vq_enorm_kernel(const float* __restrict__ E,
                                                       float* __restrict__ enorm) {
  const int w = threadIdx.x >> 6;
  const int lane = threadIdx.x & 63;
  const int k = blockIdx.x * 4 + w;
  const float4 v = *reinterpret_cast<const float4*>(E + (size_t)k * Dsz + lane * 4);
  float s = v.x * v.x + v.y * v.y + v.z * v.z + v.w * v.w;
#pragma unroll
  for (int off = 32; off > 0; off >>= 1) s += __shfl_down(s, off);
  if (lane == 0) enorm[k] = s;
}

// ---------------------------------------------------------------------------
// Kernel 1: fused X*E^T + argmin_k( ||e||^2 - 2 x.e ) over this block's K range
// grid = (Bsz/BM) * SPLITK, block = 256 threads (16 j x 16 i), 8x8 reg tile
// ---------------------------------------------------------------------------
__global__ __launch_bounds__(256) void vq_argmin_kernel(
    const float* __restrict__ X, const float* __restrict__ E,
    const float* __restrict__ enorm, float2* __restrict__ cand) {
  __shared__ float sX[BM][LDSS];
  __shared__ float sE[BN][LDSS];

  const int t = threadIdx.x;
  const int j = t & 15;   // col group: cols j + 16c
  const int i = t >> 4;   // row group: rows i + 16r
  const int mb = blockIdx.x >> 2;
  const int split = blockIdx.x & (SPLITK - 1);
  const int row0 = mb * BM;
  const int kbase0 = split * (KC_PER_SPLIT * BN);

  float minv[8];
  int mini[8];
#pragma unroll
  for (int r = 0; r < 8; ++r) { minv[r] = 3.4e38f; mini[r] = 0; }

  for (int kc = 0; kc < KC_PER_SPLIT; ++kc) {
    const int kb = kbase0 + kc * BN;
    float acc[8][8];
#pragma unroll
    for (int r = 0; r < 8; ++r)
#pragma unroll
      for (int c = 0; c < 8; ++c) acc[r][c] = 0.0f;

    for (int dc = 0; dc < Dsz / DC; ++dc) {
      __syncthreads();
      // Stage X[128][32] and E[128][32] tiles (coalesced float4, row-major LDS)
#pragma unroll
      for (int l = 0; l < 4; ++l) {
        const int q = t + 256 * l;          // 0..1023
        const int row = q >> 3;             // 0..127
        const int seg = q & 7;              // 0..7 (float4 within 32-float row)
        *reinterpret_cast<float4*>(&sX[row][seg * 4]) =
            *reinterpret_cast<const float4*>(X + (size_t)(row0 + row) * Dsz + dc * DC + seg * 4);
        *reinterpret_cast<float4*>(&sE[row][seg * 4]) =
            *reinterpret_cast<const float4*>(E + (size_t)(kb + row) * Dsz + dc * DC + seg * 4);
      }
      __syncthreads();

#pragma unroll
      for (int dd = 0; dd < DC / 4; ++dd) {
        float4 a[8];
#pragma unroll
        for (int r = 0; r < 8; ++r)
          a[r] = *reinterpret_cast<const float4*>(&sX[i + 16 * r][dd * 4]);
#pragma unroll
        for (int c = 0; c < 8; ++c) {
          const float4 b = *reinterpret_cast<const float4*>(&sE[j + 16 * c][dd * 4]);
#pragma unroll
          for (int r = 0; r < 8; ++r)
            acc[r][c] += a[r].x * b.x + a[r].y * b.y + a[r].z * b.z + a[r].w * b.w;
        }
      }
    }

    // Fold ||e||^2 and update running argmin (ascending k order per thread)
#pragma unroll
    for (int c = 0; c < 8; ++c) {
      const int kg = kb + j + 16 * c;
      const float en = enorm[kg];
#pragma unroll
      for (int r = 0; r < 8; ++r) {
        const float s = en - 2.0f * acc[r][c];
        if (s < minv[r]) { minv[r] = s; mini[r] = kg; }
      }
    }
  }

  // Cross-thread (over j) argmin reduction via LDS; first-min-index tie-break
  __syncthreads();
  float2* pairs = reinterpret_cast<float2*>(&sX[0][0]);  // [BM][17] float2
#pragma unroll
  for (int r = 0; r < 8; ++r)
    pairs[(size_t)(i + 16 * r) * 17 + j] = make_float2(minv[r], __int_as_float(mini[r]));
  __syncthreads();
  if (t < BM) {
    float bv = 3.4e38f;
    int bi = 0x7fffffff;
    for (int jj = 0; jj < 16; ++jj) {
      const float2 p = pairs[(size_t)t * 17 + jj];
      const int pi = __float_as_int(p.y);
      if (p.x < bv || (p.x == bv && pi < bi)) { bv = p.x; bi = pi; }
    }
    cand[(size_t)(row0 + t) * SPLITK + split] = make_float2(bv, __int_as_float(bi));
  }
}

// ---------------------------------------------------------------------------
// Kernel 2: merge split-K candidates, gather codebook row, loss, outputs.
// One wave per row. out layout: [B*D quantized][1 loss][B indices-as-float]
// ---------------------------------------------------------------------------
__global__ __launch_bounds__(256) void vq_finalize_kernel(
    const float* __restrict__ X, const float* __restrict__ E,
    const float2* __restrict__ cand, float* __restrict__ out) {
  const int w = threadIdx.x >> 6;
  const int lane = threadIdx.x & 63;
  const int b = blockIdx.x * 4 + w;

  float bv = 3.4e38f;
  int bi = 0x7fffffff;
#pragma unroll
  for (int s = 0; s < SPLITK; ++s) {
    const float2 p = cand[(size_t)b * SPLITK + s];  // uniform addr -> broadcast
    const int pi = __float_as_int(p.y);
    if (p.x < bv || (p.x == bv && pi < bi)) { bv = p.x; bi = pi; }
  }

  const float4 q = *reinterpret_cast<const float4*>(E + (size_t)bi * Dsz + lane * 4);
  const float4 x = *reinterpret_cast<const float4*>(X + (size_t)b * Dsz + lane * 4);
  *reinterpret_cast<float4*>(out + (size_t)b * Dsz + lane * 4) = q;  // quantized_st == q

  const float dx = x.x - q.x, dy = x.y - q.y, dz = x.z - q.z, dw = x.w - q.w;
  float s2 = dx * dx + dy * dy + dz * dz + dw * dw;
#pragma unroll
  for (int off = 32; off > 0; off >>= 1) s2 += __shfl_down(s2, off);
  if (lane == 0) {
    // loss = q_latent + 0.25*e_latent = 1.25 * mean((x-q)^2)
    atomicAdd(out + (size_t)Bsz * Dsz, s2 * (1.25f / ((float)Bsz * (float)Dsz)));
    out[(size_t)Bsz * Dsz + 1 + b] = (float)bi;  // index as float
  }
}

// ---------------------------------------------------------------------------
extern "C" void kernel_launch(void* const* d_in, const int* in_sizes, int n_in,
                              void* d_out, int out_size, void* d_ws, size_t ws_size,
                              hipStream_t stream) {
  const float* X = (const float*)d_in[0];   // [B, D] fp32
  const float* E = (const float*)d_in[1];   // [K, D] fp32
  float* out = (float*)d_out;

  float* enorm = (float*)d_ws;                                   // 16 KB
  float2* cand = (float2*)((char*)d_ws + (size_t)Ksz * sizeof(float));  // 1 MB

  // zero the loss accumulator slot (out is poisoned before every call)
  hipMemsetAsync(out + (size_t)Bsz * Dsz, 0, sizeof(float), stream);

  vq_enorm_kernel<<<Ksz / 4, 256, 0, stream>>>(E, enorm);
  vq_argmin_kernel<<<(Bsz / BM) * SPLITK, 256, 0, stream>>>(X, E, enorm, cand);
  vq_finalize_kernel<<<Bsz / 4, 256, 0, stream>>>(X, E, cand, out);
}

// Round 3
// 1349.972 us; speedup vs baseline: 2.0215x; 2.0215x over previous
//
#include <hip/hip_runtime.h>

// Problem dims (fixed by reference setup_inputs)
constexpr int Bsz = 32768;
constexpr int Ksz = 4096;
constexpr int Dsz = 256;

constexpr int KD = 512;       // stored K-dim of split buffers [hi(256) | lo(256)]
constexpr int NSLABS = 8;     // N split across blocks: 4096/8 = 512 cols per block
constexpr int CTILES = 4;     // 4 col-tiles of 128 within a slab
constexpr int NCAND = 16;     // NSLABS * 2 wave-columns (race fix: per-wn slot)
constexpr float TAU = 1e-3f;  // top-2 gap below which finalize does exact fp64 rescan

typedef __attribute__((ext_vector_type(8))) short short8;
typedef __attribute__((ext_vector_type(4))) float f32x4;

// --- fp32 -> bf16 (RNE) helpers (bit ops; no hip_bf16 dependency) -----------
__device__ __forceinline__ unsigned short f2bf(float f) {
  unsigned u = __float_as_uint(f);
  u += 0x7fffu + ((u >> 16) & 1u);
  return (unsigned short)(u >> 16);
}
__device__ __forceinline__ float bf2f(unsigned short h) {
  return __uint_as_float(((unsigned)h) << 16);
}

// ---------------------------------------------------------------------------
// Prep X: split fp32 rows into [hi | lo] bf16, row-major KD=512
// ---------------------------------------------------------------------------
__global__ __launch_bounds__(256) void vq_prep_x(const float* __restrict__ X,
                                                 unsigned short* __restrict__ X2) {
  const int tid = blockIdx.x * 256 + threadIdx.x;  // 0 .. Bsz*64-1
  const int row = tid >> 6;
  const int d4 = tid & 63;
  const float4 v = *reinterpret_cast<const float4*>(X + (size_t)row * Dsz + d4 * 4);
  ushort4 h, l;
  h.x = f2bf(v.x); l.x = f2bf(v.x - bf2f(h.x));
  h.y = f2bf(v.y); l.y = f2bf(v.y - bf2f(h.y));
  h.z = f2bf(v.z); l.z = f2bf(v.z - bf2f(h.z));
  h.w = f2bf(v.w); l.w = f2bf(v.w - bf2f(h.w));
  *reinterpret_cast<ushort4*>(X2 + (size_t)row * KD + d4 * 4) = h;
  *reinterpret_cast<ushort4*>(X2 + (size_t)row * KD + 256 + d4 * 4) = l;
}

// ---------------------------------------------------------------------------
// Prep E: split + fp32 squared norms (wave per code row)
// ---------------------------------------------------------------------------
__global__ __launch_bounds__(256) void vq_prep_e(const float* __restrict__ E,
                                                 unsigned short* __restrict__ E2,
                                                 float* __restrict__ enorm) {
  const int wid = threadIdx.x >> 6;
  const int lane = threadIdx.x & 63;
  const int k = blockIdx.x * 4 + wid;
  const float4 v = *reinterpret_cast<const float4*>(E + (size_t)k * Dsz + lane * 4);
  ushort4 h, l;
  h.x = f2bf(v.x); l.x = f2bf(v.x - bf2f(h.x));
  h.y = f2bf(v.y); l.y = f2bf(v.y - bf2f(h.y));
  h.z = f2bf(v.z); l.z = f2bf(v.z - bf2f(h.z));
  h.w = f2bf(v.w); l.w = f2bf(v.w - bf2f(h.w));
  *reinterpret_cast<ushort4*>(E2 + (size_t)k * KD + lane * 4) = h;
  *reinterpret_cast<ushort4*>(E2 + (size_t)k * KD + 256 + lane * 4) = l;
  float s = v.x * v.x + v.y * v.y + v.z * v.z + v.w * v.w;
#pragma unroll
  for (int off = 32; off > 0; off >>= 1) s += __shfl_down(s, off);
  if (lane == 0) enorm[k] = s;
}

// ---------------------------------------------------------------------------
// Fused bf16 MFMA GEMM (3-pass split as K=768 schedule) + top-2 argmin.
// Block: 256 thr (4 waves, 2x2), 128x128 tile; 24 K-steps of BK=32 per col-tile.
// grid = (Bsz/128) * NSLABS; block covers 128 rows x 512 cols (4 col-tiles).
// cand[row][slab*2+wn] = (m1, i1_as_float, m2, 0)  -- per-wave slot (no race)
// ---------------------------------------------------------------------------
__global__ __launch_bounds__(256, 2) void vq_gemm_argmin(
    const unsigned short* __restrict__ X2, const unsigned short* __restrict__ E2,
    const float* __restrict__ enorm, float4* __restrict__ cand) {
  __shared__ unsigned short sA[128 * 32];
  __shared__ unsigned short sB[128 * 32];

  const int t = threadIdx.x;
  const int lane = t & 63;
  const int wid = t >> 6;
  const int wm = wid >> 1, wn = wid & 1;
  const int mb = blockIdx.x >> 3;
  const int slab = blockIdx.x & 7;
  const int row0 = mb * 128;
  const int col0 = slab * 512;

  const int srow = lane >> 2;   // staging: 16 rows per 1KB wave-instruction
  const int sslot = lane & 3;   // 16B slot within a 64B LDS row

  float m1[16], m2[16];
  int i1[16];
#pragma unroll
  for (int r = 0; r < 16; ++r) { m1[r] = 3.4e38f; m2[r] = 3.4e38f; i1[r] = 0x7fffffff; }

  for (int ct = 0; ct < CTILES; ++ct) {
    const int colt = col0 + ct * 128;
    f32x4 acc[4][4];
#pragma unroll
    for (int a = 0; a < 4; ++a)
#pragma unroll
      for (int b = 0; b < 4; ++b) acc[a][b] = f32x4{0.f, 0.f, 0.f, 0.f};

    for (int step = 0; step < 24; ++step) {
      // segment schedule: 0-7: xh*eh, 8-15: xl*eh, 16-23: xh*el
      const int seg = step >> 3;
      const int k32 = (step & 7) * 32;
      const int aoff = ((seg == 1) ? 256 : 0) + k32;
      const int boff = ((seg == 2) ? 256 : 0) + k32;

      __syncthreads();  // previous step's LDS reads complete
#pragma unroll
      for (int c = 0; c < 2; ++c) {
        const int r0 = wid * 32 + c * 16;
        const unsigned short* gA =
            X2 + (size_t)(row0 + r0 + srow) * KD + aoff + sslot * 8;
        __builtin_amdgcn_global_load_lds(
            (const __attribute__((address_space(1))) void*)gA,
            (__attribute__((address_space(3))) void*)(sA + r0 * 32), 16, 0, 0);
        const unsigned short* gB =
            E2 + (size_t)(colt + r0 + srow) * KD + boff + sslot * 8;
        __builtin_amdgcn_global_load_lds(
            (const __attribute__((address_space(1))) void*)gB,
            (__attribute__((address_space(3))) void*)(sB + r0 * 32), 16, 0, 0);
      }
      __syncthreads();  // staging visible to all waves

      short8 af[4], bf[4];
#pragma unroll
      for (int a = 0; a < 4; ++a)
        af[a] = *reinterpret_cast<const short8*>(
            sA + (wm * 64 + a * 16 + (lane & 15)) * 32 + (lane >> 4) * 8);
#pragma unroll
      for (int b = 0; b < 4; ++b)
        bf[b] = *reinterpret_cast<const short8*>(
            sB + (wn * 64 + b * 16 + (lane & 15)) * 32 + (lane >> 4) * 8);
#pragma unroll
      for (int a = 0; a < 4; ++a)
#pragma unroll
        for (int b = 0; b < 4; ++b)
          acc[a][b] = __builtin_amdgcn_mfma_f32_16x16x32_bf16(af[a], bf[b], acc[a][b], 0, 0, 0);
    }

    // Epilogue: s = ||e||^2 - 2 x.e ; per-lane running top-2 (cols ascending)
#pragma unroll
    for (int b = 0; b < 4; ++b) {
      const int colg = colt + wn * 64 + b * 16 + (lane & 15);
      const float en = enorm[colg];
#pragma unroll
      for (int a = 0; a < 4; ++a) {
#pragma unroll
        for (int q = 0; q < 4; ++q) {
          const float s = en - 2.0f * acc[a][b][q];
          const int r = a * 4 + q;
          if (s < m1[r]) { m2[r] = m1[r]; m1[r] = s; i1[r] = colg; }
          else if (s < m2[r]) { m2[r] = s; }
        }
      }
    }
  }

  // Cross-lane merge over the 16 column-lanes (xor bits 0..3), then store cand
#pragma unroll
  for (int r = 0; r < 16; ++r) {
    float v1 = m1[r], v2 = m2[r];
    int ii = i1[r];
#pragma unroll
    for (int mbit = 1; mbit <= 8; mbit <<= 1) {
      const float ov1 = __shfl_xor(v1, mbit);
      const float ov2 = __shfl_xor(v2, mbit);
      const int oi = __shfl_xor(ii, mbit);
      const float nm2 = fminf(fmaxf(v1, ov1), fminf(v2, ov2));
      if (ov1 < v1 || (ov1 == v1 && oi < ii)) { v1 = ov1; ii = oi; }
      v2 = nm2;
    }
    if ((lane & 15) == 0) {
      const int rowg = row0 + wm * 64 + (r >> 2) * 16 + (lane >> 4) * 4 + (r & 3);
      cand[(size_t)rowg * NCAND + slab * 2 + wn] = make_float4(v1, __int_as_float(ii), v2, 0.f);
    }
  }
}

// ---------------------------------------------------------------------------
// Finalize: merge 16 candidates per row; exact fp64 rescan if gap < TAU;
// gather code row, write quantized + loss + index. One wave per row.
// ---------------------------------------------------------------------------
__global__ __launch_bounds__(256) void vq_finalize(
    const float* __restrict__ X, const float* __restrict__ E,
    const float4* __restrict__ cand, float* __restrict__ out) {
  const int wid = threadIdx.x >> 6;
  const int lane = threadIdx.x & 63;
  const int b = blockIdx.x * 4 + wid;

  float v1 = 3.4e38f, v2 = 3.4e38f;
  int ii = 0x7fffffff;
  if (lane < NCAND) {
    const float4 c = cand[(size_t)b * NCAND + lane];
    v1 = c.x; ii = __float_as_int(c.y); v2 = c.z;
  }
#pragma unroll
  for (int mbit = 1; mbit <= 8; mbit <<= 1) {
    const float ov1 = __shfl_xor(v1, mbit);
    const float ov2 = __shfl_xor(v2, mbit);
    const int oi = __shfl_xor(ii, mbit);
    const float nm2 = fminf(fmaxf(v1, ov1), fminf(v2, ov2));
    if (ov1 < v1 || (ov1 == v1 && oi < ii)) { v1 = ov1; ii = oi; }
    v2 = nm2;
  }
  v1 = __shfl(v1, 0); v2 = __shfl(v2, 0); ii = __shfl(ii, 0);

  if (v2 - v1 < TAU) {
    // exact fp64 rescan over all codes (rare; wave-parallel over k)
    double bestv = 1.7e308;
    int besti = 0x7fffffff;
    const float4* xr = reinterpret_cast<const float4*>(X + (size_t)b * Dsz);
    for (int k = lane; k < Ksz; k += 64) {
      const float4* er = reinterpret_cast<const float4*>(E + (size_t)k * Dsz);
      double en = 0.0, xe = 0.0;
      for (int d = 0; d < 64; ++d) {
        const float4 e4 = er[d];
        const float4 x4 = xr[d];
        en += (double)e4.x * e4.x + (double)e4.y * e4.y +
              (double)e4.z * e4.z + (double)e4.w * e4.w;
        xe += (double)x4.x * e4.x + (double)x4.y * e4.y +
              (double)x4.z * e4.z + (double)x4.w * e4.w;
      }
      const double dist = en - 2.0 * xe;
      if (dist < bestv || (dist == bestv && k < besti)) { bestv = dist; besti = k; }
    }
#pragma unroll
    for (int mbit = 1; mbit <= 32; mbit <<= 1) {
      const double obv = __shfl_xor(bestv, mbit);
      const int obi = __shfl_xor(besti, mbit);
      if (obv < bestv || (obv == bestv && obi < besti)) { bestv = obv; besti = obi; }
    }
    ii = besti;
  }

  const float4 q = *reinterpret_cast<const float4*>(E + (size_t)ii * Dsz + lane * 4);
  const float4 x = *reinterpret_cast<const float4*>(X + (size_t)b * Dsz + lane * 4);
  *reinterpret_cast<float4*>(out + (size_t)b * Dsz + lane * 4) = q;

  const float dx = x.x - q.x, dy = x.y - q.y, dz = x.z - q.z, dw = x.w - q.w;
  float s2 = dx * dx + dy * dy + dz * dz + dw * dw;
#pragma unroll
  for (int off = 32; off > 0; off >>= 1) s2 += __shfl_down(s2, off);
  if (lane == 0) {
    atomicAdd(out + (size_t)Bsz * Dsz, s2 * (1.25f / ((float)Bsz * (float)Dsz)));
    out[(size_t)Bsz * Dsz + 1 + b] = (float)ii;
  }
}

// ---------------------------------------------------------------------------
extern "C" void kernel_launch(void* const* d_in, const int* in_sizes, int n_in,
                              void* d_out, int out_size, void* d_ws, size_t ws_size,
                              hipStream_t stream) {
  const float* X = (const float*)d_in[0];  // [B, D] fp32
  const float* E = (const float*)d_in[1];  // [K, D] fp32
  float* out = (float*)d_out;

  char* ws = (char*)d_ws;
  float* enorm = (float*)ws;                                             // 16 KB
  unsigned short* X2 = (unsigned short*)(ws + (16 << 10));               // 32 MB
  unsigned short* E2 = (unsigned short*)(ws + (16 << 10) + (32 << 20));  // 4 MB
  float4* cand = (float4*)(ws + (16 << 10) + (36 << 20));                // 8 MB

  hipMemsetAsync(out + (size_t)Bsz * Dsz, 0, sizeof(float), stream);

  vq_prep_x<<<Bsz * 64 / 256, 256, 0, stream>>>(X, X2);
  vq_prep_e<<<Ksz / 4, 256, 0, stream>>>(E, E2, enorm);
  vq_gemm_argmin<<<(Bsz / 128) * NSLABS, 256, 0, stream>>>(X2, E2, enorm, cand);
  vq_finalize<<<Bsz / 4, 256, 0, stream>>>(X, E, cand, out);
}

// Round 5
// 964.967 us; speedup vs baseline: 2.8281x; 1.3990x over previous
//
#include <hip/hip_runtime.h>

// Problem dims (fixed by reference setup_inputs)
constexpr int Bsz = 32768;
constexpr int Ksz = 4096;
constexpr int Dsz = 256;

constexpr int KD = 512;       // stored K-dim of split buffers [hi(256) | lo(256)]
constexpr int NSLABS = 8;     // N split across blocks: 4096/8 = 512 cols per block
constexpr int CTILES = 4;     // 4 col-tiles of 128 within a slab
constexpr int NCAND = 16;     // NSLABS * 2 wave-columns (per-wave slot, no race)
constexpr int NFBLK = Bsz / 4;  // finalize blocks (4 rows each) = 8192
constexpr float TAU = 1e-3f;  // top-2 gap below which finalize does exact fp64 rescan

typedef __attribute__((ext_vector_type(8))) short short8;
typedef __attribute__((ext_vector_type(4))) float f32x4;

// --- fp32 -> bf16 (RNE) helpers (bit ops; no hip_bf16 dependency) -----------
__device__ __forceinline__ unsigned short f2bf(float f) {
  unsigned u = __float_as_uint(f);
  u += 0x7fffu + ((u >> 16) & 1u);
  return (unsigned short)(u >> 16);
}
__device__ __forceinline__ float bf2f(unsigned short h) {
  return __uint_as_float(((unsigned)h) << 16);
}

// ---------------------------------------------------------------------------
// Prep X: split fp32 rows into [hi | lo] bf16, row-major KD=512
// ---------------------------------------------------------------------------
__global__ __launch_bounds__(256) void vq_prep_x(const float* __restrict__ X,
                                                 unsigned short* __restrict__ X2) {
  const int tid = blockIdx.x * 256 + threadIdx.x;  // 0 .. Bsz*64-1
  const int row = tid >> 6;
  const int d4 = tid & 63;
  const float4 v = *reinterpret_cast<const float4*>(X + (size_t)row * Dsz + d4 * 4);
  ushort4 h, l;
  h.x = f2bf(v.x); l.x = f2bf(v.x - bf2f(h.x));
  h.y = f2bf(v.y); l.y = f2bf(v.y - bf2f(h.y));
  h.z = f2bf(v.z); l.z = f2bf(v.z - bf2f(h.z));
  h.w = f2bf(v.w); l.w = f2bf(v.w - bf2f(h.w));
  *reinterpret_cast<ushort4*>(X2 + (size_t)row * KD + d4 * 4) = h;
  *reinterpret_cast<ushort4*>(X2 + (size_t)row * KD + 256 + d4 * 4) = l;
}

// ---------------------------------------------------------------------------
// Prep E: split + fp32 squared norms (wave per code row)
// ---------------------------------------------------------------------------
__global__ __launch_bounds__(256) void vq_prep_e(const float* __restrict__ E,
                                                 unsigned short* __restrict__ E2,
                                                 float* __restrict__ enorm) {
  const int wid = threadIdx.x >> 6;
  const int lane = threadIdx.x & 63;
  const int k = blockIdx.x * 4 + wid;
  const float4 v = *reinterpret_cast<const float4*>(E + (size_t)k * Dsz + lane * 4);
  ushort4 h, l;
  h.x = f2bf(v.x); l.x = f2bf(v.x - bf2f(h.x));
  h.y = f2bf(v.y); l.y = f2bf(v.y - bf2f(h.y));
  h.z = f2bf(v.z); l.z = f2bf(v.z - bf2f(h.z));
  h.w = f2bf(v.w); l.w = f2bf(v.w - bf2f(h.w));
  *reinterpret_cast<ushort4*>(E2 + (size_t)k * KD + lane * 4) = h;
  *reinterpret_cast<ushort4*>(E2 + (size_t)k * KD + 256 + lane * 4) = l;
  float s = v.x * v.x + v.y * v.y + v.z * v.z + v.w * v.w;
#pragma unroll
  for (int off = 32; off > 0; off >>= 1) s += __shfl_down(s, off);
  if (lane == 0) enorm[k] = s;
}

// ---------------------------------------------------------------------------
// Fused bf16 MFMA GEMM (3-pass split as K=768 schedule) + top-2 argmin.
// Block: 256 thr (4 waves, 2x2), 128x128 tile; 24 K-steps of BK=32 per col-tile.
// grid = (Bsz/128) * NSLABS; block covers 128 rows x 512 cols (4 col-tiles).
// cand[row][slab*2+wn] = (m1, i1_as_float, m2, 0)  -- per-wave slot (no race)
// ---------------------------------------------------------------------------
__global__ __launch_bounds__(256, 2) void vq_gemm_argmin(
    const unsigned short* __restrict__ X2, const unsigned short* __restrict__ E2,
    const float* __restrict__ enorm, float4* __restrict__ cand) {
  __shared__ unsigned short sA[128 * 32];
  __shared__ unsigned short sB[128 * 32];

  const int t = threadIdx.x;
  const int lane = t & 63;
  const int wid = t >> 6;
  const int wm = wid >> 1, wn = wid & 1;
  const int mb = blockIdx.x >> 3;
  const int slab = blockIdx.x & 7;
  const int row0 = mb * 128;
  const int col0 = slab * 512;

  const int srow = lane >> 2;   // staging: 16 rows per 1KB wave-instruction
  const int sslot = lane & 3;   // 16B slot within a 64B LDS row

  float m1[16], m2[16];
  int i1[16];
#pragma unroll
  for (int r = 0; r < 16; ++r) { m1[r] = 3.4e38f; m2[r] = 3.4e38f; i1[r] = 0x7fffffff; }

  for (int ct = 0; ct < CTILES; ++ct) {
    const int colt = col0 + ct * 128;
    f32x4 acc[4][4];
#pragma unroll
    for (int a = 0; a < 4; ++a)
#pragma unroll
      for (int b = 0; b < 4; ++b) acc[a][b] = f32x4{0.f, 0.f, 0.f, 0.f};

    for (int step = 0; step < 24; ++step) {
      // segment schedule: 0-7: xh*eh, 8-15: xl*eh, 16-23: xh*el
      const int seg = step >> 3;
      const int k32 = (step & 7) * 32;
      const int aoff = ((seg == 1) ? 256 : 0) + k32;
      const int boff = ((seg == 2) ? 256 : 0) + k32;

      __syncthreads();  // previous step's LDS reads complete
#pragma unroll
      for (int c = 0; c < 2; ++c) {
        const int r0 = wid * 32 + c * 16;
        const unsigned short* gA =
            X2 + (size_t)(row0 + r0 + srow) * KD + aoff + sslot * 8;
        __builtin_amdgcn_global_load_lds(
            (const __attribute__((address_space(1))) void*)gA,
            (__attribute__((address_space(3))) void*)(sA + r0 * 32), 16, 0, 0);
        const unsigned short* gB =
            E2 + (size_t)(colt + r0 + srow) * KD + boff + sslot * 8;
        __builtin_amdgcn_global_load_lds(
            (const __attribute__((address_space(1))) void*)gB,
            (__attribute__((address_space(3))) void*)(sB + r0 * 32), 16, 0, 0);
      }
      __syncthreads();  // staging visible to all waves

      short8 af[4], bf[4];
#pragma unroll
      for (int a = 0; a < 4; ++a)
        af[a] = *reinterpret_cast<const short8*>(
            sA + (wm * 64 + a * 16 + (lane & 15)) * 32 + (lane >> 4) * 8);
#pragma unroll
      for (int b = 0; b < 4; ++b)
        bf[b] = *reinterpret_cast<const short8*>(
            sB + (wn * 64 + b * 16 + (lane & 15)) * 32 + (lane >> 4) * 8);
#pragma unroll
      for (int a = 0; a < 4; ++a)
#pragma unroll
        for (int b = 0; b < 4; ++b)
          acc[a][b] = __builtin_amdgcn_mfma_f32_16x16x32_bf16(af[a], bf[b], acc[a][b], 0, 0, 0);
    }

    // Epilogue: s = ||e||^2 - 2 x.e ; per-lane running top-2 (cols ascending)
#pragma unroll
    for (int b = 0; b < 4; ++b) {
      const int colg = colt + wn * 64 + b * 16 + (lane & 15);
      const float en = enorm[colg];
#pragma unroll
      for (int a = 0; a < 4; ++a) {
#pragma unroll
        for (int q = 0; q < 4; ++q) {
          const float s = en - 2.0f * acc[a][b][q];
          const int r = a * 4 + q;
          if (s < m1[r]) { m2[r] = m1[r]; m1[r] = s; i1[r] = colg; }
          else if (s < m2[r]) { m2[r] = s; }
        }
      }
    }
  }

  // Cross-lane merge over the 16 column-lanes (xor bits 0..3), then store cand
#pragma unroll
  for (int r = 0; r < 16; ++r) {
    float v1 = m1[r], v2 = m2[r];
    int ii = i1[r];
#pragma unroll
    for (int mbit = 1; mbit <= 8; mbit <<= 1) {
      const float ov1 = __shfl_xor(v1, mbit);
      const float ov2 = __shfl_xor(v2, mbit);
      const int oi = __shfl_xor(ii, mbit);
      const float nm2 = fminf(fmaxf(v1, ov1), fminf(v2, ov2));
      if (ov1 < v1 || (ov1 == v1 && oi < ii)) { v1 = ov1; ii = oi; }
      v2 = nm2;
    }
    if ((lane & 15) == 0) {
      const int rowg = row0 + wm * 64 + (r >> 2) * 16 + (lane >> 4) * 4 + (r & 3);
      cand[(size_t)rowg * NCAND + slab * 2 + wn] = make_float4(v1, __int_as_float(ii), v2, 0.f);
    }
  }
}

// ---------------------------------------------------------------------------
// Finalize: merge 16 candidates per row; exact fp64 rescan if gap < TAU;
// gather code row, write quantized + index; block-local loss partial (no atomic).
// One wave per row, 4 rows per block.
// ---------------------------------------------------------------------------
__global__ __launch_bounds__(256) void vq_finalize(
    const float* __restrict__ X, const float* __restrict__ E,
    const float4* __restrict__ cand, float* __restrict__ out,
    float* __restrict__ partial) {
  __shared__ float ls[4];
  const int wid = threadIdx.x >> 6;
  const int lane = threadIdx.x & 63;
  const int b = blockIdx.x * 4 + wid;

  float v1 = 3.4e38f, v2 = 3.4e38f;
  int ii = 0x7fffffff;
  if (lane < NCAND) {
    const float4 c = cand[(size_t)b * NCAND + lane];
    v1 = c.x; ii = __float_as_int(c.y); v2 = c.z;
  }
#pragma unroll
  for (int mbit = 1; mbit <= 8; mbit <<= 1) {
    const float ov1 = __shfl_xor(v1, mbit);
    const float ov2 = __shfl_xor(v2, mbit);
    const int oi = __shfl_xor(ii, mbit);
    const float nm2 = fminf(fmaxf(v1, ov1), fminf(v2, ov2));
    if (ov1 < v1 || (ov1 == v1 && oi < ii)) { v1 = ov1; ii = oi; }
    v2 = nm2;
  }
  v1 = __shfl(v1, 0); v2 = __shfl(v2, 0); ii = __shfl(ii, 0);

  if (v2 - v1 < TAU) {
    // exact fp64 rescan over all codes (rare; wave-parallel over k)
    double bestv = 1.7e308;
    int besti = 0x7fffffff;
    const float4* xr = reinterpret_cast<const float4*>(X + (size_t)b * Dsz);
    for (int k = lane; k < Ksz; k += 64) {
      const float4* er = reinterpret_cast<const float4*>(E + (size_t)k * Dsz);
      double en = 0.0, xe = 0.0;
      for (int d = 0; d < 64; ++d) {
        const float4 e4 = er[d];
        const float4 x4 = xr[d];
        en += (double)e4.x * e4.x + (double)e4.y * e4.y +
              (double)e4.z * e4.z + (double)e4.w * e4.w;
        xe += (double)x4.x * e4.x + (double)x4.y * e4.y +
              (double)x4.z * e4.z + (double)x4.w * e4.w;
      }
      const double dist = en - 2.0 * xe;
      if (dist < bestv || (dist == bestv && k < besti)) { bestv = dist; besti = k; }
    }
#pragma unroll
    for (int mbit = 1; mbit <= 32; mbit <<= 1) {
      const double obv = __shfl_xor(bestv, mbit);
      const int obi = __shfl_xor(besti, mbit);
      if (obv < bestv || (obv == bestv && obi < besti)) { bestv = obv; besti = obi; }
    }
    ii = besti;
  }

  const float4 q = *reinterpret_cast<const float4*>(E + (size_t)ii * Dsz + lane * 4);
  const float4 x = *reinterpret_cast<const float4*>(X + (size_t)b * Dsz + lane * 4);
  *reinterpret_cast<float4*>(out + (size_t)b * Dsz + lane * 4) = q;

  const float dx = x.x - q.x, dy = x.y - q.y, dz = x.z - q.z, dw = x.w - q.w;
  float s2 = dx * dx + dy * dy + dz * dz + dw * dw;
#pragma unroll
  for (int off = 32; off > 0; off >>= 1) s2 += __shfl_down(s2, off);
  if (lane == 0) {
    ls[wid] = s2;
    out[(size_t)Bsz * Dsz + 1 + b] = (float)ii;
  }
  __syncthreads();
  if (threadIdx.x == 0)
    partial[blockIdx.x] = ls[0] + ls[1] + ls[2] + ls[3];
}

// ---------------------------------------------------------------------------
// Loss reduce: one block sums the 8192 per-block partials -> out[B*D]
// ---------------------------------------------------------------------------
__global__ __launch_bounds__(256) void vq_loss_reduce(const float* __restrict__ partial,
                                                      float* __restrict__ out) {
  __shared__ float ls[4];
  const int wid = threadIdx.x >> 6;
  const int lane = threadIdx.x & 63;
  float s = 0.f;
  for (int i = threadIdx.x; i < NFBLK; i += 256) s += partial[i];
#pragma unroll
  for (int off = 32; off > 0; off >>= 1) s += __shfl_down(s, off);
  if (lane == 0) ls[wid] = s;
  __syncthreads();
  if (threadIdx.x == 0)
    out[(size_t)Bsz * Dsz] = (ls[0] + ls[1] + ls[2] + ls[3]) *
                             (1.25f / ((float)Bsz * (float)Dsz));
}

// ---------------------------------------------------------------------------
extern "C" void kernel_launch(void* const* d_in, const int* in_sizes, int n_in,
                              void* d_out, int out_size, void* d_ws, size_t ws_size,
                              hipStream_t stream) {
  const float* X = (const float*)d_in[0];  // [B, D] fp32
  const float* E = (const float*)d_in[1];  // [K, D] fp32
  float* out = (float*)d_out;

  char* ws = (char*)d_ws;
  float* enorm = (float*)ws;                                             // 16 KB
  unsigned short* X2 = (unsigned short*)(ws + (16 << 10));               // 32 MB
  unsigned short* E2 = (unsigned short*)(ws + (16 << 10) + (32 << 20));  // 4 MB
  float4* cand = (float4*)(ws + (16 << 10) + (36 << 20));                // 8 MB
  float* partial = (float*)(ws + (16 << 10) + (44 << 20));               // 32 KB

  vq_prep_x<<<Bsz * 64 / 256, 256, 0, stream>>>(X, X2);
  vq_prep_e<<<Ksz / 4, 256, 0, stream>>>(E, E2, enorm);
  vq_gemm_argmin<<<(Bsz / 128) * NSLABS, 256, 0, stream>>>(X2, E2, enorm, cand);
  vq_finalize<<<NFBLK, 256, 0, stream>>>(X, E, cand, out, partial);
  vq_loss_reduce<<<1, 256, 0, stream>>>(partial, out);
}

// Round 6
// 384.296 us; speedup vs baseline: 7.1014x; 2.5110x over previous
//
#include <hip/hip_runtime.h>

// Problem dims (fixed by reference setup_inputs)
constexpr int Bsz = 32768;
constexpr int Ksz = 4096;
constexpr int Dsz = 256;

constexpr int KD = 512;        // stored K-dim of split buffers [hi(256) | lo(256)]
constexpr int NSLABS = 4;      // N split across blocks: 1024 cols per block
constexpr int CTILES = 8;      // 8 col-tiles of 128 within a slab
constexpr int NCAND = 8;       // NSLABS * 2 wave-columns (per-wave slot)
constexpr int NFBLK = Bsz / 4; // finalize blocks (4 rows each)
constexpr float TAU = 1e-3f;   // top-2 gap below which finalize exact-compares in fp64

typedef __attribute__((ext_vector_type(8))) short short8;
typedef __attribute__((ext_vector_type(4))) float f32x4;

// --- fp32 -> bf16 (RNE) helpers (bit ops; no hip_bf16 dependency) -----------
__device__ __forceinline__ unsigned short f2bf(float f) {
  unsigned u = __float_as_uint(f);
  u += 0x7fffu + ((u >> 16) & 1u);
  return (unsigned short)(u >> 16);
}
__device__ __forceinline__ float bf2f(unsigned short h) {
  return __uint_as_float(((unsigned)h) << 16);
}

// ---------------------------------------------------------------------------
// Prep X: split fp32 rows into [hi | lo] bf16, row-major KD=512
// ---------------------------------------------------------------------------
__global__ __launch_bounds__(256) void vq_prep_x(const float* __restrict__ X,
                                                 unsigned short* __restrict__ X2) {
  const int tid = blockIdx.x * 256 + threadIdx.x;
  const int row = tid >> 6;
  const int d4 = tid & 63;
  const float4 v = *reinterpret_cast<const float4*>(X + (size_t)row * Dsz + d4 * 4);
  ushort4 h, l;
  h.x = f2bf(v.x); l.x = f2bf(v.x - bf2f(h.x));
  h.y = f2bf(v.y); l.y = f2bf(v.y - bf2f(h.y));
  h.z = f2bf(v.z); l.z = f2bf(v.z - bf2f(h.z));
  h.w = f2bf(v.w); l.w = f2bf(v.w - bf2f(h.w));
  *reinterpret_cast<ushort4*>(X2 + (size_t)row * KD + d4 * 4) = h;
  *reinterpret_cast<ushort4*>(X2 + (size_t)row * KD + 256 + d4 * 4) = l;
}

// ---------------------------------------------------------------------------
// Prep E: split + fp32 squared norms (wave per code row)
// ---------------------------------------------------------------------------
__global__ __launch_bounds__(256) void vq_prep_e(const float* __restrict__ E,
                                                 unsigned short* __restrict__ E2,
                                                 float* __restrict__ enorm) {
  const int wid = threadIdx.x >> 6;
  const int lane = threadIdx.x & 63;
  const int k = blockIdx.x * 4 + wid;
  const float4 v = *reinterpret_cast<const float4*>(E + (size_t)k * Dsz + lane * 4);
  ushort4 h, l;
  h.x = f2bf(v.x); l.x = f2bf(v.x - bf2f(h.x));
  h.y = f2bf(v.y); l.y = f2bf(v.y - bf2f(h.y));
  h.z = f2bf(v.z); l.z = f2bf(v.z - bf2f(h.z));
  h.w = f2bf(v.w); l.w = f2bf(v.w - bf2f(h.w));
  *reinterpret_cast<ushort4*>(E2 + (size_t)k * KD + lane * 4) = h;
  *reinterpret_cast<ushort4*>(E2 + (size_t)k * KD + 256 + lane * 4) = l;
  float s = v.x * v.x + v.y * v.y + v.z * v.z + v.w * v.w;
#pragma unroll
  for (int off = 32; off > 0; off >>= 1) s += __shfl_down(s, off);
  if (lane == 0) enorm[k] = s;
}

// ---------------------------------------------------------------------------
// Fused bf16 MFMA GEMM + top-2 argmin (values AND indices).
// Block: 256 thr (4 waves 2x2), 128-row x 1024-col panel as 8 col-tiles of 128.
// Per k32 chunk: stage [hi|lo] once into 128B LDS rows (XOR slot-swizzle via
// pre-swizzled global source, linear LDS dest, swizzled ds_read), then 48 MFMA:
// ah*bh + al*bh + ah*bl.  XCD swizzle: mb = bid&255 -> slab siblings co-XCD.
// cand[row][slab*2+wn] = (m1, i1, m2, i2)
// ---------------------------------------------------------------------------
__global__ __launch_bounds__(256, 2) void vq_gemm_argmin(
    const unsigned short* __restrict__ X2, const unsigned short* __restrict__ E2,
    const float* __restrict__ enorm, float4* __restrict__ cand) {
  __shared__ unsigned short sA[128 * 64];
  __shared__ unsigned short sB[128 * 64];

  const int t = threadIdx.x;
  const int lane = t & 63;
  const int wid = t >> 6;
  const int wm = wid >> 1, wn = wid & 1;
  const int mb = blockIdx.x & 255;   // Bsz/128 = 256 row-panels
  const int slab = blockIdx.x >> 8;  // 4 slabs
  const int row0 = mb * 128;
  const int col0 = slab * 1024;

  // staging: lane l writes LDS linearly at row (r0 + l>>3), 16B slot (l&7);
  // it must FETCH the data belonging to logical slot (l&7)^(row&7).
  const int rr = lane >> 3;
  const int sl = (lane & 7) ^ rr;
  const int sloff = (sl & 3) * 8 + ((sl & 4) << 6);  // shorts: hi s*8 | lo 256+s*8

  // fragment read: logical slot g=(lane>>4) (hi) / 4+g (lo); phys = log ^ (lane&7)
  const int l15 = lane & 15;
  const int fsel = ((lane >> 4) ^ (lane & 7)) * 8;   // shorts; lo = fsel ^ 32

  float m1[16], m2[16];
  int i1[16], i2[16];
#pragma unroll
  for (int r = 0; r < 16; ++r) {
    m1[r] = 3.4e38f; m2[r] = 3.4e38f; i1[r] = 0x7fffffff; i2[r] = 0x7fffffff;
  }

  for (int ct = 0; ct < CTILES; ++ct) {
    const int colt = col0 + ct * 128;
    f32x4 acc[4][4];
#pragma unroll
    for (int a = 0; a < 4; ++a)
#pragma unroll
      for (int b = 0; b < 4; ++b) acc[a][b] = f32x4{0.f, 0.f, 0.f, 0.f};

    for (int c = 0; c < 8; ++c) {
      const int kb = c * 32;
      __syncthreads();  // previous chunk's LDS reads complete
      const int rbase = wid * 32;
#pragma unroll
      for (int qi = 0; qi < 4; ++qi) {
        const int r0 = rbase + qi * 8;
        const unsigned short* gA =
            X2 + (size_t)(row0 + r0 + rr) * KD + kb + sloff;
        __builtin_amdgcn_global_load_lds(
            (const __attribute__((address_space(1))) void*)gA,
            (__attribute__((address_space(3))) void*)(sA + r0 * 64), 16, 0, 0);
        const unsigned short* gB =
            E2 + (size_t)(colt + r0 + rr) * KD + kb + sloff;
        __builtin_amdgcn_global_load_lds(
            (const __attribute__((address_space(1))) void*)gB,
            (__attribute__((address_space(3))) void*)(sB + r0 * 64), 16, 0, 0);
      }
      __syncthreads();  // staging visible

      short8 ah[4], bh[4];
#pragma unroll
      for (int a = 0; a < 4; ++a)
        ah[a] = *reinterpret_cast<const short8*>(
            sA + (wm * 64 + a * 16 + l15) * 64 + fsel);
#pragma unroll
      for (int b = 0; b < 4; ++b)
        bh[b] = *reinterpret_cast<const short8*>(
            sB + (wn * 64 + b * 16 + l15) * 64 + fsel);
#pragma unroll
      for (int a = 0; a < 4; ++a)
#pragma unroll
        for (int b = 0; b < 4; ++b)
          acc[a][b] = __builtin_amdgcn_mfma_f32_16x16x32_bf16(ah[a], bh[b], acc[a][b], 0, 0, 0);

      short8 al[4];
#pragma unroll
      for (int a = 0; a < 4; ++a)
        al[a] = *reinterpret_cast<const short8*>(
            sA + (wm * 64 + a * 16 + l15) * 64 + (fsel ^ 32));
#pragma unroll
      for (int a = 0; a < 4; ++a)
#pragma unroll
        for (int b = 0; b < 4; ++b)
          acc[a][b] = __builtin_amdgcn_mfma_f32_16x16x32_bf16(al[a], bh[b], acc[a][b], 0, 0, 0);

      short8 bl[4];
#pragma unroll
      for (int b = 0; b < 4; ++b)
        bl[b] = *reinterpret_cast<const short8*>(
            sB + (wn * 64 + b * 16 + l15) * 64 + (fsel ^ 32));
#pragma unroll
      for (int a = 0; a < 4; ++a)
#pragma unroll
        for (int b = 0; b < 4; ++b)
          acc[a][b] = __builtin_amdgcn_mfma_f32_16x16x32_bf16(ah[a], bl[b], acc[a][b], 0, 0, 0);
    }

    // Epilogue: s = ||e||^2 - 2 x.e ; running top-2 with indices (cols ascend)
#pragma unroll
    for (int b = 0; b < 4; ++b) {
      const int colg = colt + wn * 64 + b * 16 + l15;
      const float en = enorm[colg];
#pragma unroll
      for (int a = 0; a < 4; ++a) {
#pragma unroll
        for (int q = 0; q < 4; ++q) {
          const float s = en - 2.0f * acc[a][b][q];
          const int r = a * 4 + q;
          if (s < m1[r]) {
            m2[r] = m1[r]; i2[r] = i1[r]; m1[r] = s; i1[r] = colg;
          } else if (s < m2[r]) {
            m2[r] = s; i2[r] = colg;
          }
        }
      }
    }
  }

  // Cross-lane merge over the 16 column-lanes (xor 1,2,4,8), then store cand
#pragma unroll
  for (int r = 0; r < 16; ++r) {
    float v1 = m1[r], v2 = m2[r];
    int ii1 = i1[r], ii2 = i2[r];
#pragma unroll
    for (int mbit = 1; mbit <= 8; mbit <<= 1) {
      const float ov1 = __shfl_xor(v1, mbit);
      const float ov2 = __shfl_xor(v2, mbit);
      const int oi1 = __shfl_xor(ii1, mbit);
      const int oi2 = __shfl_xor(ii2, mbit);
      if (ov1 < v1 || (ov1 == v1 && oi1 < ii1)) {
        float nv2 = v1; int ni2 = ii1;
        if (ov2 < nv2) { nv2 = ov2; ni2 = oi2; }
        v1 = ov1; ii1 = oi1; v2 = nv2; ii2 = ni2;
      } else if (ov1 < v2) {
        v2 = ov1; ii2 = oi1;
      }
    }
    if (l15 == 0) {
      const int rowg = row0 + wm * 64 + (r >> 2) * 16 + (lane >> 4) * 4 + (r & 3);
      cand[(size_t)rowg * NCAND + slab * 2 + wn] =
          make_float4(v1, __int_as_float(ii1), v2, __int_as_float(ii2));
    }
  }
}

// ---------------------------------------------------------------------------
// Finalize: merge 8 candidates per row; if top-2 gap < TAU, exact fp64 compare
// of just those two codes (wave-parallel over D). Gather, write, loss partial.
// ---------------------------------------------------------------------------
__global__ __launch_bounds__(256) void vq_finalize(
    const float* __restrict__ X, const float* __restrict__ E,
    const float4* __restrict__ cand, float* __restrict__ out,
    float* __restrict__ partial) {
  __shared__ float ls[4];
  const int wid = threadIdx.x >> 6;
  const int lane = threadIdx.x & 63;
  const int b = blockIdx.x * 4 + wid;

  float v1 = 3.4e38f, v2 = 3.4e38f;
  int ii1 = 0x7fffffff, ii2 = 0x7fffffff;
  if (lane < NCAND) {
    const float4 c = cand[(size_t)b * NCAND + lane];
    v1 = c.x; ii1 = __float_as_int(c.y);
    v2 = c.z; ii2 = __float_as_int(c.w);
  }
#pragma unroll
  for (int mbit = 1; mbit <= 4; mbit <<= 1) {
    const float ov1 = __shfl_xor(v1, mbit);
    const float ov2 = __shfl_xor(v2, mbit);
    const int oi1 = __shfl_xor(ii1, mbit);
    const int oi2 = __shfl_xor(ii2, mbit);
    if (ov1 < v1 || (ov1 == v1 && oi1 < ii1)) {
      float nv2 = v1; int ni2 = ii1;
      if (ov2 < nv2) { nv2 = ov2; ni2 = oi2; }
      v1 = ov1; ii1 = oi1; v2 = nv2; ii2 = ni2;
    } else if (ov1 < v2) {
      v2 = ov1; ii2 = oi1;
    }
  }
  v1 = __shfl(v1, 0); v2 = __shfl(v2, 0);
  ii1 = __shfl(ii1, 0); ii2 = __shfl(ii2, 0);

  const float4 x = *reinterpret_cast<const float4*>(X + (size_t)b * Dsz + lane * 4);

  if (v2 - v1 < TAU) {
    // exact fp64 ||x-e||^2 for the two candidates only
    const float4 e1 = *reinterpret_cast<const float4*>(E + (size_t)ii1 * Dsz + lane * 4);
    const float4 e2 = *reinterpret_cast<const float4*>(E + (size_t)ii2 * Dsz + lane * 4);
    double d1 = ((double)x.x - e1.x) * ((double)x.x - e1.x) +
                ((double)x.y - e1.y) * ((double)x.y - e1.y) +
                ((double)x.z - e1.z) * ((double)x.z - e1.z) +
                ((double)x.w - e1.w) * ((double)x.w - e1.w);
    double d2 = ((double)x.x - e2.x) * ((double)x.x - e2.x) +
                ((double)x.y - e2.y) * ((double)x.y - e2.y) +
                ((double)x.z - e2.z) * ((double)x.z - e2.z) +
                ((double)x.w - e2.w) * ((double)x.w - e2.w);
#pragma unroll
    for (int mbit = 1; mbit <= 32; mbit <<= 1) {
      d1 += __shfl_xor(d1, mbit);
      d2 += __shfl_xor(d2, mbit);
    }
    if (d2 < d1 || (d2 == d1 && ii2 < ii1)) ii1 = ii2;
  }

  const float4 q = *reinterpret_cast<const float4*>(E + (size_t)ii1 * Dsz + lane * 4);
  *reinterpret_cast<float4*>(out + (size_t)b * Dsz + lane * 4) = q;

  const float dx = x.x - q.x, dy = x.y - q.y, dz = x.z - q.z, dw = x.w - q.w;
  float s2 = dx * dx + dy * dy + dz * dz + dw * dw;
#pragma unroll
  for (int off = 32; off > 0; off >>= 1) s2 += __shfl_down(s2, off);
  if (lane == 0) {
    ls[wid] = s2;
    out[(size_t)Bsz * Dsz + 1 + b] = (float)ii1;
  }
  __syncthreads();
  if (threadIdx.x == 0)
    partial[blockIdx.x] = ls[0] + ls[1] + ls[2] + ls[3];
}

// ---------------------------------------------------------------------------
// Loss reduce: one block sums the 8192 per-block partials -> out[B*D]
// ---------------------------------------------------------------------------
__global__ __launch_bounds__(256) void vq_loss_reduce(const float* __restrict__ partial,
                                                      float* __restrict__ out) {
  __shared__ float ls[4];
  const int wid = threadIdx.x >> 6;
  const int lane = threadIdx.x & 63;
  float s = 0.f;
  for (int i = threadIdx.x; i < NFBLK; i += 256) s += partial[i];
#pragma unroll
  for (int off = 32; off > 0; off >>= 1) s += __shfl_down(s, off);
  if (lane == 0) ls[wid] = s;
  __syncthreads();
  if (threadIdx.x == 0)
    out[(size_t)Bsz * Dsz] = (ls[0] + ls[1] + ls[2] + ls[3]) *
                             (1.25f / ((float)Bsz * (float)Dsz));
}

// ---------------------------------------------------------------------------
extern "C" void kernel_launch(void* const* d_in, const int* in_sizes, int n_in,
                              void* d_out, int out_size, void* d_ws, size_t ws_size,
                              hipStream_t stream) {
  const float* X = (const float*)d_in[0];  // [B, D] fp32
  const float* E = (const float*)d_in[1];  // [K, D] fp32
  float* out = (float*)d_out;

  char* ws = (char*)d_ws;
  float* enorm = (float*)ws;                                             // 16 KB
  unsigned short* X2 = (unsigned short*)(ws + (16 << 10));               // 32 MB
  unsigned short* E2 = (unsigned short*)(ws + (16 << 10) + (32 << 20));  // 4 MB
  float4* cand = (float4*)(ws + (16 << 10) + (36 << 20));                // 4 MB
  float* partial = (float*)(ws + (16 << 10) + (40 << 20));               // 32 KB

  vq_prep_x<<<Bsz * 64 / 256, 256, 0, stream>>>(X, X2);
  vq_prep_e<<<Ksz / 4, 256, 0, stream>>>(E, E2, enorm);
  vq_gemm_argmin<<<(Bsz / 128) * NSLABS, 256, 0, stream>>>(X2, E2, enorm, cand);
  vq_finalize<<<NFBLK, 256, 0, stream>>>(X, E, cand, out, partial);
  vq_loss_reduce<<<1, 256, 0, stream>>>(partial, out);
}